// Round 1
// baseline (386.918 us; speedup 1.0000x reference)
//
#include <hip/hip_runtime.h>

// Problem constants
#define BB 4
#define SS 2048
#define DM 256
#define NH 4
#define DH 64
#define NROW (BB*SS)          // 8192
#define NE   (3*DM)           // 768
#define HEAD_ELEMS (BB*NH*SS*DH)  // 2097152 per tensor (q or k or v)

#define LDS_STRIDE 68         // 64 + 4 pad, keeps 16B alignment, breaks worst bank conflicts

// ---------------------------------------------------------------------------
// QKV projection: qkv[row][e] = sum_d x[row][d] * W[e][d] + b[e]
// Scatter into workspace as q/k/v each in [B, H, S, DH] layout.
// Tile: 64 rows x 64 cols, K staged in 64-chunks, transposed LDS so the
// inner loop reads are contiguous ds_read_b128.
// ---------------------------------------------------------------------------
__global__ __launch_bounds__(256) void qkv_proj(const float* __restrict__ x,
                                                const float* __restrict__ W,
                                                const float* __restrict__ bias,
                                                float* __restrict__ ws_qkv) {
    __shared__ __align__(16) float xs[64 * LDS_STRIDE];   // [k][m]
    __shared__ __align__(16) float wws[64 * LDS_STRIDE];  // [k][n]
    const int rb  = blockIdx.x * 64;   // row base (b*s)
    const int eb  = blockIdx.y * 64;   // output-feature base
    const int tid = threadIdx.x;
    const int tr  = tid >> 4;          // 0..15 -> rows tr*4..tr*4+3
    const int tc  = tid & 15;          // 0..15 -> cols tc*4..tc*4+3

    float acc[4][4] = {};

    for (int k0 = 0; k0 < DM; k0 += 64) {
        #pragma unroll
        for (int i = 0; i < 4; ++i) {
            int idx = tid + 256 * i;       // 0..1023
            int r   = idx >> 4;            // 0..63
            int c4  = (idx & 15) * 4;      // 0..60
            float4 vx = *(const float4*)&x[(size_t)(rb + r) * DM + k0 + c4];
            xs[(c4 + 0) * LDS_STRIDE + r] = vx.x;
            xs[(c4 + 1) * LDS_STRIDE + r] = vx.y;
            xs[(c4 + 2) * LDS_STRIDE + r] = vx.z;
            xs[(c4 + 3) * LDS_STRIDE + r] = vx.w;
            float4 vw = *(const float4*)&W[(size_t)(eb + r) * DM + k0 + c4];
            wws[(c4 + 0) * LDS_STRIDE + r] = vw.x;
            wws[(c4 + 1) * LDS_STRIDE + r] = vw.y;
            wws[(c4 + 2) * LDS_STRIDE + r] = vw.z;
            wws[(c4 + 3) * LDS_STRIDE + r] = vw.w;
        }
        __syncthreads();
        #pragma unroll 8
        for (int kk = 0; kk < 64; ++kk) {
            float4 a4 = *(const float4*)&xs[kk * LDS_STRIDE + tr * 4];
            float4 b4 = *(const float4*)&wws[kk * LDS_STRIDE + tc * 4];
            const float a[4] = {a4.x, a4.y, a4.z, a4.w};
            const float b[4] = {b4.x, b4.y, b4.z, b4.w};
            #pragma unroll
            for (int i = 0; i < 4; ++i)
                #pragma unroll
                for (int j = 0; j < 4; ++j)
                    acc[i][j] += a[i] * b[j];
        }
        __syncthreads();
    }

    // Epilogue: bias add + scatter to q/k/v [B,H,S,DH]
    #pragma unroll
    for (int i = 0; i < 4; ++i) {
        int row = rb + tr * 4 + i;
        int b   = row >> 11;           // /2048
        int s   = row & 2047;
        #pragma unroll
        for (int j = 0; j < 4; ++j) {
            int e    = eb + tc * 4 + j;
            int part = e >> 8;         // 0=q 1=k 2=v
            int dm   = e & 255;
            int h    = dm >> 6;
            int dh   = dm & 63;
            float val = acc[i][j] + bias[e];
            ws_qkv[(size_t)part * HEAD_ELEMS +
                   (((size_t)(b * NH + h) * SS + s) * DH + dh)] = val;
        }
    }
}

// ---------------------------------------------------------------------------
// Flash attention (fp32, vector ALU). One block per (q-tile of 64, b*h).
// 256 threads; thread (tq,tk) owns 4x4 of the 64x64 score tile and 4x4 of
// the 64x64 output tile. P round-trips through LDS (aliased onto K buffer).
// ---------------------------------------------------------------------------
__global__ __launch_bounds__(256) void attn(const float* __restrict__ q,
                                            const float* __restrict__ k,
                                            const float* __restrict__ v,
                                            float* __restrict__ out) {
    __shared__ __align__(16) float Qs[64 * LDS_STRIDE];   // [d][qr], pre-scaled
    __shared__ __align__(16) float KPs[64 * LDS_STRIDE];  // K: [d][kr]  /  P: [kr][qr]
    __shared__ __align__(16) float Vs[64 * LDS_STRIDE];   // [kr][d]

    const int q0   = blockIdx.x * 64;
    const int bh   = blockIdx.y;
    const size_t base = (size_t)bh * SS * DH;
    const int tid  = threadIdx.x;
    const int tq   = tid >> 4;   // 0..15 -> q rows tq*4..+3
    const int tk   = tid & 15;   // 0..15 -> k cols / d cols tk*4..+3
    const float scale = 0.125f;  // 1/sqrt(64)

    // Load Q tile transposed, folding in the softmax scale
    #pragma unroll
    for (int i = 0; i < 4; ++i) {
        int idx = tid + 256 * i;
        int r   = idx >> 4;
        int c4  = (idx & 15) * 4;
        float4 vq = *(const float4*)&q[base + (size_t)(q0 + r) * DH + c4];
        Qs[(c4 + 0) * LDS_STRIDE + r] = vq.x * scale;
        Qs[(c4 + 1) * LDS_STRIDE + r] = vq.y * scale;
        Qs[(c4 + 2) * LDS_STRIDE + r] = vq.z * scale;
        Qs[(c4 + 3) * LDS_STRIDE + r] = vq.w * scale;
    }

    float m_i[4] = {-3.0e38f, -3.0e38f, -3.0e38f, -3.0e38f};
    float l_i[4] = {0.f, 0.f, 0.f, 0.f};
    float o[4][4] = {};

    for (int kt = 0; kt < SS; kt += 64) {
        __syncthreads();   // protect KPs/Vs overwrite vs previous iteration's reads
        // Stage K (transposed) and V (natural) tiles
        #pragma unroll
        for (int i = 0; i < 4; ++i) {
            int idx = tid + 256 * i;
            int r   = idx >> 4;
            int c4  = (idx & 15) * 4;
            float4 vk = *(const float4*)&k[base + (size_t)(kt + r) * DH + c4];
            KPs[(c4 + 0) * LDS_STRIDE + r] = vk.x;
            KPs[(c4 + 1) * LDS_STRIDE + r] = vk.y;
            KPs[(c4 + 2) * LDS_STRIDE + r] = vk.z;
            KPs[(c4 + 3) * LDS_STRIDE + r] = vk.w;
            float4 vv = *(const float4*)&v[base + (size_t)(kt + r) * DH + c4];
            *(float4*)&Vs[r * LDS_STRIDE + c4] = vv;
        }
        __syncthreads();

        // S = Q K^T (pre-scaled)
        float sc[4][4] = {};
        #pragma unroll 8
        for (int d = 0; d < 64; ++d) {
            float4 a4 = *(const float4*)&Qs[d * LDS_STRIDE + tq * 4];
            float4 b4 = *(const float4*)&KPs[d * LDS_STRIDE + tk * 4];
            const float a[4] = {a4.x, a4.y, a4.z, a4.w};
            const float b[4] = {b4.x, b4.y, b4.z, b4.w};
            #pragma unroll
            for (int i = 0; i < 4; ++i)
                #pragma unroll
                for (int j = 0; j < 4; ++j)
                    sc[i][j] += a[i] * b[j];
        }

        __syncthreads();   // everyone done reading K before P overwrites it

        // Online softmax + write P (transposed [kr][qr]) into KPs
        #pragma unroll
        for (int i = 0; i < 4; ++i) {
            float rmax = fmaxf(fmaxf(sc[i][0], sc[i][1]), fmaxf(sc[i][2], sc[i][3]));
            rmax = fmaxf(rmax, __shfl_xor(rmax, 1));
            rmax = fmaxf(rmax, __shfl_xor(rmax, 2));
            rmax = fmaxf(rmax, __shfl_xor(rmax, 4));
            rmax = fmaxf(rmax, __shfl_xor(rmax, 8));
            float m_new = fmaxf(m_i[i], rmax);
            float alpha = __expf(m_i[i] - m_new);
            m_i[i] = m_new;
            float rsum = 0.f;
            #pragma unroll
            for (int j = 0; j < 4; ++j) {
                sc[i][j] = __expf(sc[i][j] - m_new);
                rsum += sc[i][j];
            }
            rsum += __shfl_xor(rsum, 1);
            rsum += __shfl_xor(rsum, 2);
            rsum += __shfl_xor(rsum, 4);
            rsum += __shfl_xor(rsum, 8);
            l_i[i] = l_i[i] * alpha + rsum;
            #pragma unroll
            for (int j = 0; j < 4; ++j) {
                o[i][j] *= alpha;
                KPs[(tk * 4 + j) * LDS_STRIDE + tq * 4 + i] = sc[i][j];
            }
        }
        __syncthreads();

        // O += P V
        #pragma unroll 8
        for (int kr = 0; kr < 64; ++kr) {
            float4 a4 = *(const float4*)&KPs[kr * LDS_STRIDE + tq * 4];
            float4 b4 = *(const float4*)&Vs[kr * LDS_STRIDE + tk * 4];
            const float a[4] = {a4.x, a4.y, a4.z, a4.w};
            const float b[4] = {b4.x, b4.y, b4.z, b4.w};
            #pragma unroll
            for (int i = 0; i < 4; ++i)
                #pragma unroll
                for (int j = 0; j < 4; ++j)
                    o[i][j] += a[i] * b[j];
        }
    }

    // Epilogue: normalize and store [B,H,S,DH]
    #pragma unroll
    for (int i = 0; i < 4; ++i) {
        float inv = 1.0f / l_i[i];
        float4 r;
        r.x = o[i][0] * inv;
        r.y = o[i][1] * inv;
        r.z = o[i][2] * inv;
        r.w = o[i][3] * inv;
        *(float4*)&out[base + (size_t)(q0 + tq * 4 + i) * DH + tk * 4] = r;
    }
}

extern "C" void kernel_launch(void* const* d_in, const int* in_sizes, int n_in,
                              void* d_out, int out_size, void* d_ws, size_t ws_size,
                              hipStream_t stream) {
    const float* x    = (const float*)d_in[0];   // [4,2048,256]
    const float* Wq   = (const float*)d_in[1];   // [768,256]
    const float* bq   = (const float*)d_in[2];   // [768]
    float* ws  = (float*)d_ws;                   // q|k|v each HEAD_ELEMS floats
    float* out = (float*)d_out;                  // [4,4,2048,64]

    qkv_proj<<<dim3(NROW / 64, NE / 64), 256, 0, stream>>>(x, Wq, bq, ws);

    const float* qp = ws;
    const float* kp = ws + (size_t)HEAD_ELEMS;
    const float* vp = ws + (size_t)2 * HEAD_ELEMS;
    attn<<<dim3(SS / 64, BB * NH), 256, 0, stream>>>(qp, kp, vp, out);
}

// Round 2
// 166.865 us; speedup vs baseline: 2.3188x; 2.3188x over previous
//
#include <hip/hip_runtime.h>

// Problem constants
#define BB 4
#define SS 2048
#define DM 256
#define NH 4
#define DH 64
#define NROW (BB*SS)          // 8192
#define NE   (3*DM)           // 768
#define HEAD_ELEMS (BB*NH*SS*DH)  // 2097152 per tensor

#define LDS_STRIDE 68         // fp32 SGEMM tiles: 64 + 4 pad

typedef _Float16 half_t;
typedef __attribute__((ext_vector_type(8))) _Float16 half8;
typedef __attribute__((ext_vector_type(4))) _Float16 half4;
typedef __attribute__((ext_vector_type(4))) float floatx4;

#define KPAD 72               // fp16 attn LDS stride (64 + 8), keeps 16B align

// ---------------------------------------------------------------------------
// QKV projection (fp32 vector SGEMM, unchanged math). Epilogue now writes:
//   q  -> fp16, pre-scaled by 1/sqrt(64)=0.125, layout [B,H,S,DH]
//   k  -> fp16, layout [B,H,S,DH]
//   v  -> fp16 TRANSPOSED, layout [B,H,DH,S]  (for attn's B-operand reads)
// ---------------------------------------------------------------------------
__global__ __launch_bounds__(256) void qkv_proj(const float* __restrict__ x,
                                                const float* __restrict__ W,
                                                const float* __restrict__ bias,
                                                half_t* __restrict__ qh,
                                                half_t* __restrict__ kh,
                                                half_t* __restrict__ vt) {
    __shared__ __align__(16) float xs[64 * LDS_STRIDE];   // [k][m]
    __shared__ __align__(16) float wws[64 * LDS_STRIDE];  // [k][n]
    const int rb  = blockIdx.x * 64;
    const int eb  = blockIdx.y * 64;
    const int tid = threadIdx.x;
    const int tr  = tid >> 4;
    const int tc  = tid & 15;

    float acc[4][4] = {};

    for (int k0 = 0; k0 < DM; k0 += 64) {
        #pragma unroll
        for (int i = 0; i < 4; ++i) {
            int idx = tid + 256 * i;
            int r   = idx >> 4;
            int c4  = (idx & 15) * 4;
            float4 vx = *(const float4*)&x[(size_t)(rb + r) * DM + k0 + c4];
            xs[(c4 + 0) * LDS_STRIDE + r] = vx.x;
            xs[(c4 + 1) * LDS_STRIDE + r] = vx.y;
            xs[(c4 + 2) * LDS_STRIDE + r] = vx.z;
            xs[(c4 + 3) * LDS_STRIDE + r] = vx.w;
            float4 vw = *(const float4*)&W[(size_t)(eb + r) * DM + k0 + c4];
            wws[(c4 + 0) * LDS_STRIDE + r] = vw.x;
            wws[(c4 + 1) * LDS_STRIDE + r] = vw.y;
            wws[(c4 + 2) * LDS_STRIDE + r] = vw.z;
            wws[(c4 + 3) * LDS_STRIDE + r] = vw.w;
        }
        __syncthreads();
        #pragma unroll 8
        for (int kk = 0; kk < 64; ++kk) {
            float4 a4 = *(const float4*)&xs[kk * LDS_STRIDE + tr * 4];
            float4 b4 = *(const float4*)&wws[kk * LDS_STRIDE + tc * 4];
            const float a[4] = {a4.x, a4.y, a4.z, a4.w};
            const float b[4] = {b4.x, b4.y, b4.z, b4.w};
            #pragma unroll
            for (int i = 0; i < 4; ++i)
                #pragma unroll
                for (int j = 0; j < 4; ++j)
                    acc[i][j] += a[i] * b[j];
        }
        __syncthreads();
    }

    #pragma unroll
    for (int i = 0; i < 4; ++i) {
        int row = rb + tr * 4 + i;
        int b   = row >> 11;
        int s   = row & 2047;
        #pragma unroll
        for (int j = 0; j < 4; ++j) {
            int e    = eb + tc * 4 + j;
            int part = e >> 8;         // 0=q 1=k 2=v
            int dm   = e & 255;
            int h    = dm >> 6;
            int dh   = dm & 63;
            int bh   = b * NH + h;
            float val = acc[i][j] + bias[e];
            if (part == 0) {
                qh[((size_t)bh * SS + s) * DH + dh] = (half_t)(val * 0.125f);
            } else if (part == 1) {
                kh[((size_t)bh * SS + s) * DH + dh] = (half_t)val;
            } else {
                vt[((size_t)bh * DH + dh) * SS + s] = (half_t)val;
            }
        }
    }
}

// ---------------------------------------------------------------------------
// Flash attention, fp16 MFMA, S^T trick.
// Block = 256 thr (4 waves); wave owns 16 q rows; block q-tile = 64.
// Per K-tile (64 kr):
//   S^T[kr][q] = K·Q^T via mfma_f32_16x16x32_f16 (A=K from LDS, B=Q in regs)
//   C-layout of S^T == A-layout of 16x16x16f16 -> P stays in registers.
//   O[q][d]  += P·V via mfma_f32_16x16x16f16 (B=V^T from LDS, ds_read_b64)
// ---------------------------------------------------------------------------
__global__ __launch_bounds__(256) void attn(const half_t* __restrict__ qh,
                                            const half_t* __restrict__ kh,
                                            const half_t* __restrict__ vt,
                                            float* __restrict__ out) {
    __shared__ __align__(16) half_t Ks[64 * KPAD];    // [kr][d]
    __shared__ __align__(16) half_t Vts[64 * KPAD];   // [d][kr]

    const int q0   = blockIdx.x * 64;
    const int bh   = blockIdx.y;
    const size_t base = (size_t)bh * SS * DH;
    const int tid  = threadIdx.x;
    const int wid  = tid >> 6;
    const int lane = tid & 63;
    const int quad = lane >> 4;
    const int col  = lane & 15;   // q index within wave's 16-row strip

    // Q B-frags, resident for the whole kernel (pre-scaled in qkv_proj)
    half8 bq0, bq1;
    {
        int s = q0 + wid * 16 + col;
        bq0 = *(const half8*)&qh[base + (size_t)s * DH + quad * 8];
        bq1 = *(const half8*)&qh[base + (size_t)s * DH + 32 + quad * 8];
    }

    float m_i = -3.0e38f;
    float l_i = 0.0f;
    floatx4 o[4];
    #pragma unroll
    for (int dt = 0; dt < 4; ++dt) o[dt] = (floatx4){0.f, 0.f, 0.f, 0.f};

    for (int kt = 0; kt < SS; kt += 64) {
        __syncthreads();
        // Stage K [kr][d] and V^T [d][kr] tiles (16B/lane coalesced loads)
        #pragma unroll
        for (int i = 0; i < 2; ++i) {
            int gi = tid + 256 * i;       // 0..511
            int r  = gi >> 3;             // 0..63
            int c8 = (gi & 7) * 8;        // 0..56
            *(half8*)&Ks[r * KPAD + c8]  = *(const half8*)&kh[base + (size_t)(kt + r) * DH + c8];
            *(half8*)&Vts[r * KPAD + c8] = *(const half8*)&vt[base + (size_t)r * SS + kt + c8];
        }
        __syncthreads();

        // S^T = K · Q^T   (4 kr-tiles of 16 × this wave's 16 q)
        floatx4 sc[4];
        #pragma unroll
        for (int t = 0; t < 4; ++t) {
            half8 ak0 = *(const half8*)&Ks[(t * 16 + col) * KPAD + quad * 8];
            half8 ak1 = *(const half8*)&Ks[(t * 16 + col) * KPAD + 32 + quad * 8];
            floatx4 c = (floatx4){0.f, 0.f, 0.f, 0.f};
            c = __builtin_amdgcn_mfma_f32_16x16x32_f16(ak0, bq0, c, 0, 0, 0);
            c = __builtin_amdgcn_mfma_f32_16x16x32_f16(ak1, bq1, c, 0, 0, 0);
            sc[t] = c;
        }

        // Online softmax (lane owns one q column; rows kr = t*16 + quad*4 + r)
        float mloc = -3.0e38f;
        #pragma unroll
        for (int t = 0; t < 4; ++t)
            #pragma unroll
            for (int r = 0; r < 4; ++r)
                mloc = fmaxf(mloc, sc[t][r]);
        mloc = fmaxf(mloc, __shfl_xor(mloc, 16));
        mloc = fmaxf(mloc, __shfl_xor(mloc, 32));
        float m_new = fmaxf(m_i, mloc);
        float alpha = __expf(m_i - m_new);
        m_i = m_new;

        float rsum = 0.f;
        half4 pa[4];
        #pragma unroll
        for (int t = 0; t < 4; ++t) {
            float p0 = __expf(sc[t][0] - m_new);
            float p1 = __expf(sc[t][1] - m_new);
            float p2 = __expf(sc[t][2] - m_new);
            float p3 = __expf(sc[t][3] - m_new);
            rsum += p0 + p1 + p2 + p3;
            pa[t] = (half4){(half_t)p0, (half_t)p1, (half_t)p2, (half_t)p3};
        }
        rsum += __shfl_xor(rsum, 16);
        rsum += __shfl_xor(rsum, 32);
        l_i = l_i * alpha + rsum;

        // Rescale O rows (row q = quad*4 + i lives in lane quad*4+i's column)
        float ar[4];
        #pragma unroll
        for (int i = 0; i < 4; ++i) ar[i] = __shfl(alpha, quad * 4 + i);
        #pragma unroll
        for (int dt = 0; dt < 4; ++dt)
            #pragma unroll
            for (int i = 0; i < 4; ++i)
                o[dt][i] *= ar[i];

        // O += P · V  (P in A-layout already; V^T frags via ds_read_b64)
        #pragma unroll
        for (int t = 0; t < 4; ++t) {
            #pragma unroll
            for (int dt = 0; dt < 4; ++dt) {
                half4 bv = *(const half4*)&Vts[(dt * 16 + col) * KPAD + t * 16 + quad * 4];
                o[dt] = __builtin_amdgcn_mfma_f32_16x16x16f16(pa[t], bv, o[dt], 0, 0, 0);
            }
        }
    }

    // Epilogue: normalize, store fp32 [bh][s][d]
    float inv = 1.0f / l_i;
    float ir[4];
    #pragma unroll
    for (int i = 0; i < 4; ++i) ir[i] = __shfl(inv, quad * 4 + i);
    #pragma unroll
    for (int dt = 0; dt < 4; ++dt)
        #pragma unroll
        for (int i = 0; i < 4; ++i)
            out[base + (size_t)(q0 + wid * 16 + quad * 4 + i) * DH + dt * 16 + col] = o[dt][i] * ir[i];
}

extern "C" void kernel_launch(void* const* d_in, const int* in_sizes, int n_in,
                              void* d_out, int out_size, void* d_ws, size_t ws_size,
                              hipStream_t stream) {
    const float* x  = (const float*)d_in[0];   // [4,2048,256]
    const float* Wq = (const float*)d_in[1];   // [768,256]
    const float* bq = (const float*)d_in[2];   // [768]
    float* out = (float*)d_out;                // [4,4,2048,64]

    half_t* qh = (half_t*)d_ws;                        // [B,H,S,DH] fp16, pre-scaled
    half_t* kh = qh + (size_t)HEAD_ELEMS;              // [B,H,S,DH] fp16
    half_t* vt = kh + (size_t)HEAD_ELEMS;              // [B,H,DH,S] fp16

    qkv_proj<<<dim3(NROW / 64, NE / 64), 256, 0, stream>>>(x, Wq, bq, qh, kh, vt);
    attn<<<dim3(SS / 64, BB * NH), 256, 0, stream>>>(qh, kh, vt, out);
}

// Round 3
// 138.988 us; speedup vs baseline: 2.7838x; 1.2006x over previous
//
#include <hip/hip_runtime.h>

// Problem constants
#define BB 4
#define SS 2048
#define DM 256
#define NH 4
#define DH 64
#define NROW (BB*SS)          // 8192
#define NE   (3*DM)           // 768
#define HEAD_ELEMS (BB*NH*SS*DH)  // 2097152 per tensor

typedef _Float16 half_t;
typedef __attribute__((ext_vector_type(8))) _Float16 half8;
typedef __attribute__((ext_vector_type(4))) _Float16 half4;
typedef __attribute__((ext_vector_type(4))) float floatx4;

#define KPAD 72               // fp16 LDS stride (64 + 8 halfs = 144 B, 16B-aligned rows)

// ---------------------------------------------------------------------------
// QKV projection, fp16 MFMA with x = x_hi + x_lo split (W single fp16):
//   C = x_hi*W_h + x_lo*W_h  ==  x * W_h exactly (fp32 accumulate),
//   so only W's fp16 rounding remains (~2-3e-4 on qkv values).
// Block: 64 rows x 64 features, 256 thr / 4 waves, K chunks of 64.
// Epilogue: bias add, scatter q(*0.125)/k -> [B,H,S,DH] fp16, v -> [B,H,DH,S].
// ---------------------------------------------------------------------------
__global__ __launch_bounds__(256) void qkv_proj(const float* __restrict__ x,
                                                const float* __restrict__ W,
                                                const float* __restrict__ bias,
                                                half_t* __restrict__ qh,
                                                half_t* __restrict__ kh,
                                                half_t* __restrict__ vt) {
    __shared__ __align__(16) half_t Xh[64 * KPAD];  // x hi,  [m][k]
    __shared__ __align__(16) half_t Xl[64 * KPAD];  // x lo,  [m][k]
    __shared__ __align__(16) half_t Wh[64 * KPAD];  // W fp16,[n][k]

    const int rb   = blockIdx.x * 64;   // row base (b*s)
    const int nb   = blockIdx.y * 64;   // feature base
    const int tid  = threadIdx.x;
    const int wid  = tid >> 6;
    const int lane = tid & 63;
    const int quad = lane >> 4;
    const int col  = lane & 15;

    floatx4 acc[4];
    #pragma unroll
    for (int t = 0; t < 4; ++t) acc[t] = (floatx4){0.f, 0.f, 0.f, 0.f};

    for (int k0 = 0; k0 < DM; k0 += 64) {
        __syncthreads();
        // Stage x (hi/lo) and W (fp16) 64x64 tiles
        #pragma unroll
        for (int i = 0; i < 4; ++i) {
            int idx = tid + 256 * i;       // 0..1023
            int r   = idx >> 4;            // 0..63
            int c4  = (idx & 15) * 4;      // 0..60
            float4 vx = *(const float4*)&x[(size_t)(rb + r) * DM + k0 + c4];
            half4 hx, lx;
            hx.x = (half_t)vx.x; lx.x = (half_t)(vx.x - (float)hx.x);
            hx.y = (half_t)vx.y; lx.y = (half_t)(vx.y - (float)hx.y);
            hx.z = (half_t)vx.z; lx.z = (half_t)(vx.z - (float)hx.z);
            hx.w = (half_t)vx.w; lx.w = (half_t)(vx.w - (float)hx.w);
            *(half4*)&Xh[r * KPAD + c4] = hx;
            *(half4*)&Xl[r * KPAD + c4] = lx;
            float4 vw = *(const float4*)&W[(size_t)(nb + r) * DM + k0 + c4];
            half4 hw;
            hw.x = (half_t)vw.x; hw.y = (half_t)vw.y;
            hw.z = (half_t)vw.z; hw.w = (half_t)vw.w;
            *(half4*)&Wh[r * KPAD + c4] = hw;
        }
        __syncthreads();

        // A-frags for this wave's 16 rows (hoisted across n-tiles)
        half8 ah0 = *(const half8*)&Xh[(wid * 16 + col) * KPAD + quad * 8];
        half8 ah1 = *(const half8*)&Xh[(wid * 16 + col) * KPAD + 32 + quad * 8];
        half8 al0 = *(const half8*)&Xl[(wid * 16 + col) * KPAD + quad * 8];
        half8 al1 = *(const half8*)&Xl[(wid * 16 + col) * KPAD + 32 + quad * 8];

        #pragma unroll
        for (int t = 0; t < 4; ++t) {
            half8 bh0 = *(const half8*)&Wh[(t * 16 + col) * KPAD + quad * 8];
            half8 bh1 = *(const half8*)&Wh[(t * 16 + col) * KPAD + 32 + quad * 8];
            acc[t] = __builtin_amdgcn_mfma_f32_16x16x32_f16(ah0, bh0, acc[t], 0, 0, 0);
            acc[t] = __builtin_amdgcn_mfma_f32_16x16x32_f16(ah1, bh1, acc[t], 0, 0, 0);
            acc[t] = __builtin_amdgcn_mfma_f32_16x16x32_f16(al0, bh0, acc[t], 0, 0, 0);
            acc[t] = __builtin_amdgcn_mfma_f32_16x16x32_f16(al1, bh1, acc[t], 0, 0, 0);
        }
    }

    // Epilogue: bias + scatter. C[m][n]: m = quad*4+reg, n = t*16+col.
    const int mrow = rb + wid * 16 + quad * 4;
    #pragma unroll
    for (int t = 0; t < 4; ++t) {
        int e    = nb + t * 16 + col;
        float be = bias[e];
        int part = e >> 8;          // 0=q 1=k 2=v
        int dm   = e & 255;
        int h    = dm >> 6;
        int dh   = dm & 63;
        #pragma unroll
        for (int r = 0; r < 4; ++r) {
            int row = mrow + r;
            int b   = row >> 11;
            int s   = row & 2047;
            int bh_ = b * NH + h;
            float val = acc[t][r] + be;
            if (part == 0) {
                qh[((size_t)bh_ * SS + s) * DH + dh] = (half_t)(val * 0.125f);
            } else if (part == 1) {
                kh[((size_t)bh_ * SS + s) * DH + dh] = (half_t)val;
            } else {
                vt[((size_t)bh_ * DH + dh) * SS + s] = (half_t)val;
            }
        }
    }
}

// ---------------------------------------------------------------------------
// Flash attention, fp16 MFMA, S^T trick (unchanged from round 2).
// ---------------------------------------------------------------------------
__global__ __launch_bounds__(256) void attn(const half_t* __restrict__ qh,
                                            const half_t* __restrict__ kh,
                                            const half_t* __restrict__ vt,
                                            float* __restrict__ out) {
    __shared__ __align__(16) half_t Ks[64 * KPAD];    // [kr][d]
    __shared__ __align__(16) half_t Vts[64 * KPAD];   // [d][kr]

    const int q0   = blockIdx.x * 64;
    const int bh   = blockIdx.y;
    const size_t base = (size_t)bh * SS * DH;
    const int tid  = threadIdx.x;
    const int wid  = tid >> 6;
    const int lane = tid & 63;
    const int quad = lane >> 4;
    const int col  = lane & 15;

    half8 bq0, bq1;
    {
        int s = q0 + wid * 16 + col;
        bq0 = *(const half8*)&qh[base + (size_t)s * DH + quad * 8];
        bq1 = *(const half8*)&qh[base + (size_t)s * DH + 32 + quad * 8];
    }

    float m_i = -3.0e38f;
    float l_i = 0.0f;
    floatx4 o[4];
    #pragma unroll
    for (int dt = 0; dt < 4; ++dt) o[dt] = (floatx4){0.f, 0.f, 0.f, 0.f};

    for (int kt = 0; kt < SS; kt += 64) {
        __syncthreads();
        #pragma unroll
        for (int i = 0; i < 2; ++i) {
            int gi = tid + 256 * i;
            int r  = gi >> 3;
            int c8 = (gi & 7) * 8;
            *(half8*)&Ks[r * KPAD + c8]  = *(const half8*)&kh[base + (size_t)(kt + r) * DH + c8];
            *(half8*)&Vts[r * KPAD + c8] = *(const half8*)&vt[base + (size_t)r * SS + kt + c8];
        }
        __syncthreads();

        floatx4 sc[4];
        #pragma unroll
        for (int t = 0; t < 4; ++t) {
            half8 ak0 = *(const half8*)&Ks[(t * 16 + col) * KPAD + quad * 8];
            half8 ak1 = *(const half8*)&Ks[(t * 16 + col) * KPAD + 32 + quad * 8];
            floatx4 c = (floatx4){0.f, 0.f, 0.f, 0.f};
            c = __builtin_amdgcn_mfma_f32_16x16x32_f16(ak0, bq0, c, 0, 0, 0);
            c = __builtin_amdgcn_mfma_f32_16x16x32_f16(ak1, bq1, c, 0, 0, 0);
            sc[t] = c;
        }

        float mloc = -3.0e38f;
        #pragma unroll
        for (int t = 0; t < 4; ++t)
            #pragma unroll
            for (int r = 0; r < 4; ++r)
                mloc = fmaxf(mloc, sc[t][r]);
        mloc = fmaxf(mloc, __shfl_xor(mloc, 16));
        mloc = fmaxf(mloc, __shfl_xor(mloc, 32));
        float m_new = fmaxf(m_i, mloc);
        float alpha = __expf(m_i - m_new);
        m_i = m_new;

        float rsum = 0.f;
        half4 pa[4];
        #pragma unroll
        for (int t = 0; t < 4; ++t) {
            float p0 = __expf(sc[t][0] - m_new);
            float p1 = __expf(sc[t][1] - m_new);
            float p2 = __expf(sc[t][2] - m_new);
            float p3 = __expf(sc[t][3] - m_new);
            rsum += p0 + p1 + p2 + p3;
            pa[t] = (half4){(half_t)p0, (half_t)p1, (half_t)p2, (half_t)p3};
        }
        rsum += __shfl_xor(rsum, 16);
        rsum += __shfl_xor(rsum, 32);
        l_i = l_i * alpha + rsum;

        float ar[4];
        #pragma unroll
        for (int i = 0; i < 4; ++i) ar[i] = __shfl(alpha, quad * 4 + i);
        #pragma unroll
        for (int dt = 0; dt < 4; ++dt)
            #pragma unroll
            for (int i = 0; i < 4; ++i)
                o[dt][i] *= ar[i];

        #pragma unroll
        for (int t = 0; t < 4; ++t) {
            #pragma unroll
            for (int dt = 0; dt < 4; ++dt) {
                half4 bv = *(const half4*)&Vts[(dt * 16 + col) * KPAD + t * 16 + quad * 4];
                o[dt] = __builtin_amdgcn_mfma_f32_16x16x16f16(pa[t], bv, o[dt], 0, 0, 0);
            }
        }
    }

    float inv = 1.0f / l_i;
    float ir[4];
    #pragma unroll
    for (int i = 0; i < 4; ++i) ir[i] = __shfl(inv, quad * 4 + i);
    #pragma unroll
    for (int dt = 0; dt < 4; ++dt)
        #pragma unroll
        for (int i = 0; i < 4; ++i)
            out[base + (size_t)(q0 + wid * 16 + quad * 4 + i) * DH + dt * 16 + col] = o[dt][i] * ir[i];
}

extern "C" void kernel_launch(void* const* d_in, const int* in_sizes, int n_in,
                              void* d_out, int out_size, void* d_ws, size_t ws_size,
                              hipStream_t stream) {
    const float* x  = (const float*)d_in[0];   // [4,2048,256]
    const float* Wq = (const float*)d_in[1];   // [768,256]
    const float* bq = (const float*)d_in[2];   // [768]
    float* out = (float*)d_out;                // [4,4,2048,64]

    half_t* qh = (half_t*)d_ws;                        // [B,H,S,DH] fp16, pre-scaled
    half_t* kh = qh + (size_t)HEAD_ELEMS;              // [B,H,S,DH] fp16
    half_t* vt = kh + (size_t)HEAD_ELEMS;              // [B,H,DH,S] fp16

    qkv_proj<<<dim3(NROW / 64, NE / 64), 256, 0, stream>>>(x, Wq, bq, qh, kh, vt);
    attn<<<dim3(SS / 64, BB * NH), 256, 0, stream>>>(qh, kh, vt, out);
}